// Round 1
// baseline (2637.302 us; speedup 1.0000x reference)
//
#include <hip/hip_runtime.h>

#define NN 50000
#define NE 800000
#define DD 64

// ---------------- counts ----------------
__global__ void count_kernel(const int* __restrict__ recv, float* __restrict__ cnt) {
    int i = blockIdx.x * 256 + threadIdx.x;
    if (i < NE) atomicAdd(&cnt[recv[i]], 1.0f);
}

__global__ void inv_kernel(const float* __restrict__ cnt, float* __restrict__ inv) {
    int i = blockIdx.x * 256 + threadIdx.x;
    if (i < NN) inv[i] = 1.0f / fmaxf(cnt[i], 1.0f);
}

// ---------------- edge block ----------------
// 16 edges per block-iteration. Wave handles 4 edges x 64 ch:
// lane -> (el2 = lane>>4 edge-in-quad, cg = lane&15 -> channels 4*cg..4*cg+3)
__launch_bounds__(256, 2)
__global__ void edge_kernel(const float* __restrict__ edges_in,
                            const float* __restrict__ nodes_in,
                            const int* __restrict__ senders,
                            const int* __restrict__ receivers,
                            const float* __restrict__ W,    // [192][64]
                            const float* __restrict__ bias, // [64]
                            float* __restrict__ edges_out,
                            float* __restrict__ agg) {
    __shared__ float w_lds[192 * 64];     // 48 KB, natural [k][c]
    __shared__ float e_lds[16][196];      // pad 196: (4*row+k)%32 banks, 16B-aligned rows
    const int t = threadIdx.x;
    for (int i = t; i < 192 * 64; i += 256) w_lds[i] = W[i];
    const int lane = t & 63;
    const int wid  = t >> 6;
    const int cg   = lane & 15;
    const int el2  = lane >> 4;
    const int c0   = cg * 4;
    const float4 bv = *(const float4*)(bias + c0);

    for (int g = blockIdx.x; g < NE / 16; g += gridDim.x) {
        const int ebase = g * 16;
        __syncthreads();  // previous iteration's e_lds reads done (also orders W load on iter 0)
        #pragma unroll
        for (int rep = 0; rep < 4; ++rep) {
            const int i = rep * 4 + wid;
            const int e = ebase + i;
            e_lds[i][lane]       = edges_in[(size_t)e * DD + lane];
            const int s = senders[e];
            const int r = receivers[e];
            e_lds[i][64 + lane]  = nodes_in[(size_t)s * DD + lane];
            e_lds[i][128 + lane] = nodes_in[(size_t)r * DD + lane];
        }
        __syncthreads();
        const int ei = wid * 4 + el2;
        const int e  = ebase + ei;
        float a0 = 0.f, a1 = 0.f, a2 = 0.f, a3 = 0.f;
        const float* erow = &e_lds[ei][0];
        #pragma unroll 4
        for (int k0 = 0; k0 < 192; k0 += 4) {
            const float4 ev = *(const float4*)(erow + k0);
            const float4 w0 = *(const float4*)(&w_lds[(k0 + 0) * 64 + c0]);
            const float4 w1 = *(const float4*)(&w_lds[(k0 + 1) * 64 + c0]);
            const float4 w2 = *(const float4*)(&w_lds[(k0 + 2) * 64 + c0]);
            const float4 w3 = *(const float4*)(&w_lds[(k0 + 3) * 64 + c0]);
            a0 += ev.x * w0.x; a1 += ev.x * w0.y; a2 += ev.x * w0.z; a3 += ev.x * w0.w;
            a0 += ev.y * w1.x; a1 += ev.y * w1.y; a2 += ev.y * w1.z; a3 += ev.y * w1.w;
            a0 += ev.z * w2.x; a1 += ev.z * w2.y; a2 += ev.z * w2.z; a3 += ev.z * w2.w;
            a0 += ev.w * w3.x; a1 += ev.w * w3.y; a2 += ev.w * w3.z; a3 += ev.w * w3.w;
        }
        float4 o;
        o.x = fmaxf(a0 + bv.x, 0.f);
        o.y = fmaxf(a1 + bv.y, 0.f);
        o.z = fmaxf(a2 + bv.z, 0.f);
        o.w = fmaxf(a3 + bv.w, 0.f);
        *(float4*)(edges_out + (size_t)e * DD + c0) = o;
        const int r = receivers[e];
        float* ap = agg + (size_t)r * DD + c0;
        atomicAdd(ap + 0, o.x);
        atomicAdd(ap + 1, o.y);
        atomicAdd(ap + 2, o.z);
        atomicAdd(ap + 3, o.w);
    }
}

// ---------------- node block ----------------
__launch_bounds__(256, 3)
__global__ void node_kernel(const float* __restrict__ nodes_in,
                            const float* __restrict__ agg,
                            const float* __restrict__ inv,
                            const float* __restrict__ W,    // [128][64]
                            const float* __restrict__ bias, // [64]
                            float* __restrict__ nodes_out) {
    __shared__ float w_lds[128 * 64];     // 32 KB
    __shared__ float x_lds[16][132];      // pad 132
    const int t = threadIdx.x;
    for (int i = t; i < 128 * 64; i += 256) w_lds[i] = W[i];
    const int lane = t & 63;
    const int wid  = t >> 6;
    const int cg   = lane & 15;
    const int nl2  = lane >> 4;
    const int c0   = cg * 4;
    const float4 bv = *(const float4*)(bias + c0);

    for (int g = blockIdx.x; g < NN / 16; g += gridDim.x) {  // 3125 groups exactly
        const int vbase = g * 16;
        __syncthreads();
        #pragma unroll
        for (int rep = 0; rep < 4; ++rep) {
            const int i = rep * 4 + wid;
            const int v = vbase + i;
            x_lds[i][lane]      = nodes_in[(size_t)v * DD + lane];
            x_lds[i][64 + lane] = agg[(size_t)v * DD + lane] * inv[v];
        }
        __syncthreads();
        const int ni = wid * 4 + nl2;
        const int v  = vbase + ni;
        float a0 = 0.f, a1 = 0.f, a2 = 0.f, a3 = 0.f;
        const float* xrow = &x_lds[ni][0];
        #pragma unroll 4
        for (int k0 = 0; k0 < 128; k0 += 4) {
            const float4 ev = *(const float4*)(xrow + k0);
            const float4 w0 = *(const float4*)(&w_lds[(k0 + 0) * 64 + c0]);
            const float4 w1 = *(const float4*)(&w_lds[(k0 + 1) * 64 + c0]);
            const float4 w2 = *(const float4*)(&w_lds[(k0 + 2) * 64 + c0]);
            const float4 w3 = *(const float4*)(&w_lds[(k0 + 3) * 64 + c0]);
            a0 += ev.x * w0.x; a1 += ev.x * w0.y; a2 += ev.x * w0.z; a3 += ev.x * w0.w;
            a0 += ev.y * w1.x; a1 += ev.y * w1.y; a2 += ev.y * w1.z; a3 += ev.y * w1.w;
            a0 += ev.z * w2.x; a1 += ev.z * w2.y; a2 += ev.z * w2.z; a3 += ev.z * w2.w;
            a0 += ev.w * w3.x; a1 += ev.w * w3.y; a2 += ev.w * w3.z; a3 += ev.w * w3.w;
        }
        float4 o;
        o.x = fmaxf(a0 + bv.x, 0.f);
        o.y = fmaxf(a1 + bv.y, 0.f);
        o.z = fmaxf(a2 + bv.z, 0.f);
        o.w = fmaxf(a3 + bv.w, 0.f);
        *(float4*)(nodes_out + (size_t)v * DD + c0) = o;
    }
}

// ---------------- final: LN + MLP + projection ----------------
__launch_bounds__(256, 2)
__global__ void final_kernel(const float* __restrict__ nodes,
                             const float* __restrict__ gamma,
                             const float* __restrict__ beta,
                             const float* __restrict__ W1, const float* __restrict__ b1,
                             const float* __restrict__ W2, const float* __restrict__ b2,
                             const float* __restrict__ Wp, const float* __restrict__ bp,
                             float* __restrict__ out) {
    __shared__ float w1_lds[64 * 128];   // [k][c] 32 KB
    __shared__ float w2_lds[128 * 64];   // [k][c] 32 KB
    const int t = threadIdx.x;
    for (int i = t; i < 64 * 128; i += 256) w1_lds[i] = W1[i];
    for (int i = t; i < 128 * 64; i += 256) w2_lds[i] = W2[i];
    const int lane = t & 63;
    const int wid  = t >> 6;
    const float gm  = gamma[lane], bt = beta[lane];
    const float b1a = b1[lane], b1b = b1[64 + lane];
    const float b2l = b2[lane];
    const float wpl = Wp[lane];
    const float bp0 = bp[0];
    __syncthreads();

    for (int v = blockIdx.x * 4 + wid; v < NN; v += gridDim.x * 4) {
        const float x = nodes[(size_t)v * DD + lane];
        float s = x;
        #pragma unroll
        for (int off = 32; off; off >>= 1) s += __shfl_xor(s, off, 64);
        const float mu = s * (1.0f / 64.0f);
        const float d  = x - mu;
        float q = d * d;
        #pragma unroll
        for (int off = 32; off; off >>= 1) q += __shfl_xor(q, off, 64);
        const float xn = d * rsqrtf(q * (1.0f / 64.0f) + 1e-5f) * gm + bt;

        float h0 = 0.f, h1 = 0.f;
        #pragma unroll 8
        for (int k = 0; k < 64; ++k) {
            const float xk = __shfl(xn, k, 64);
            h0 += xk * w1_lds[k * 128 + lane];
            h1 += xk * w1_lds[k * 128 + 64 + lane];
        }
        h0 = fmaxf(h0 + b1a, 0.f);
        h1 = fmaxf(h1 + b1b, 0.f);

        float o = 0.f;
        #pragma unroll 8
        for (int k = 0; k < 128; ++k) {
            const float hk = __shfl((k < 64) ? h0 : h1, k & 63, 64);
            o += hk * w2_lds[k * 64 + lane];
        }
        o += b2l;

        float p = o * wpl;
        #pragma unroll
        for (int off = 32; off; off >>= 1) p += __shfl_xor(p, off, 64);
        if (lane == 0) out[v] = p + bp0;
    }
}

extern "C" void kernel_launch(void* const* d_in, const int* in_sizes, int n_in,
                              void* d_out, int out_size, void* d_ws, size_t ws_size,
                              hipStream_t stream) {
    const float* nodes     = (const float*)d_in[0];
    const float* edges     = (const float*)d_in[1];
    const int*   senders   = (const int*)d_in[2];
    const int*   receivers = (const int*)d_in[3];
    const float* We        = (const float*)d_in[4];
    const float* be        = (const float*)d_in[5];
    const float* Wn        = (const float*)d_in[6];
    const float* bn        = (const float*)d_in[7];
    const float* gamma     = (const float*)d_in[8];
    const float* beta      = (const float*)d_in[9];
    const float* W1        = (const float*)d_in[10];
    const float* b1        = (const float*)d_in[11];
    const float* W2        = (const float*)d_in[12];
    const float* b2        = (const float*)d_in[13];
    const float* Wp        = (const float*)d_in[14];
    const float* bp        = (const float*)d_in[15];
    float* out = (float*)d_out;

    float* ws        = (float*)d_ws;
    float* edges_buf = ws;                                   // [E][64]  204.8 MB
    float* agg       = edges_buf + (size_t)NE * DD;          // [N][64]  12.8 MB
    float* nodes_buf = agg + (size_t)NN * DD;                // [N][64]  12.8 MB
    float* cnt       = nodes_buf + (size_t)NN * DD;          // [N]
    float* inv       = cnt + NN;                             // [N]

    hipMemsetAsync(cnt, 0, NN * sizeof(float), stream);
    count_kernel<<<(NE + 255) / 256, 256, 0, stream>>>(receivers, cnt);
    inv_kernel<<<(NN + 255) / 256, 256, 0, stream>>>(cnt, inv);

    for (int l = 0; l < 3; ++l) {
        hipMemsetAsync(agg, 0, (size_t)NN * DD * sizeof(float), stream);
        edge_kernel<<<2048, 256, 0, stream>>>(
            l == 0 ? edges : edges_buf,
            l == 0 ? nodes : nodes_buf,
            senders, receivers,
            We + (size_t)l * 192 * 64, be + (size_t)l * 64,
            edges_buf, agg);
        node_kernel<<<1024, 256, 0, stream>>>(
            l == 0 ? nodes : nodes_buf, agg, inv,
            Wn + (size_t)l * 128 * 64, bn + (size_t)l * 64,
            nodes_buf);
    }
    final_kernel<<<625, 256, 0, stream>>>(nodes_buf, gamma, beta,
                                          W1, b1, W2, b2, Wp, bp, out);
}

// Round 2
// 1211.606 us; speedup vs baseline: 2.1767x; 2.1767x over previous
//
#include <hip/hip_runtime.h>

#define NN 50000
#define NE 800000

// ================= CSR build: hist / inv / scan / scatter =================
__global__ void hist_kernel(const int* __restrict__ recv, int* __restrict__ cnt) {
    int i = blockIdx.x * 256 + threadIdx.x;
    if (i < NE) atomicAdd(&cnt[recv[i]], 1);
}

__global__ void inv_kernel(const int* __restrict__ cnt, float* __restrict__ inv) {
    int i = blockIdx.x * 256 + threadIdx.x;
    if (i < NN) inv[i] = 1.0f / (float)max(cnt[i], 1);
}

__global__ void scan1_kernel(const int* __restrict__ cnt, int* __restrict__ excl,
                             int* __restrict__ bsum) {
    const int i = blockIdx.x * 256 + threadIdx.x;
    const int lane = threadIdx.x & 63, wid = threadIdx.x >> 6;
    int orig = (i < NN) ? cnt[i] : 0;
    int x = orig;
    #pragma unroll
    for (int off = 1; off < 64; off <<= 1) {
        int y = __shfl_up(x, off, 64);
        if (lane >= off) x += y;
    }
    __shared__ int ws[4];
    if (lane == 63) ws[wid] = x;
    __syncthreads();
    int add = 0;
    for (int w = 0; w < wid; ++w) add += ws[w];
    x += add;
    if (i < NN) excl[i] = x - orig;
    if (threadIdx.x == 255) bsum[blockIdx.x] = x;
}

__global__ void scan2_kernel(int* __restrict__ bsum, int nb) {
    const int t = threadIdx.x;
    const int lane = t & 63, wid = t >> 6;
    int orig = (t < nb) ? bsum[t] : 0;
    int x = orig;
    #pragma unroll
    for (int off = 1; off < 64; off <<= 1) {
        int y = __shfl_up(x, off, 64);
        if (lane >= off) x += y;
    }
    __shared__ int ws[4];
    if (lane == 63) ws[wid] = x;
    __syncthreads();
    int add = 0;
    for (int w = 0; w < wid; ++w) add += ws[w];
    x += add;
    __syncthreads();
    if (t < nb) bsum[t] = x - orig;   // exclusive block offsets
}

__global__ void scan3_kernel(int* __restrict__ excl, const int* __restrict__ bsum) {
    const int i = blockIdx.x * 256 + threadIdx.x;
    if (i < NN) excl[i] += bsum[blockIdx.x];
    if (i == 0) excl[NN] = NE;
}

__global__ void scatter_kernel(const int* __restrict__ recv, const int* __restrict__ row_start,
                               int* __restrict__ cursor, int* __restrict__ eidx) {
    int i = blockIdx.x * 256 + threadIdx.x;
    if (i < NE) {
        int r = recv[i];
        int p = row_start[r] + atomicAdd(&cursor[r], 1);
        eidx[p] = i;
    }
}

// ================= generic M x 64 x 64 GEMM =================
// out[e] = maybe_relu(A[e] @ W + bias + P[senders[e]] + Q[receivers[e]])
// thread tile: 8 edges (stride 16) x 4 channels. 128-edge M-tiles.
__launch_bounds__(256, 3)
__global__ void gemm64_kernel(const float* __restrict__ A, int M,
                              const float* __restrict__ W,     // [64][64] k-major
                              const float* __restrict__ bias,  // [64] or null
                              const float* __restrict__ P,     // [NN][64] or null
                              const float* __restrict__ Q,     // [NN][64] or null
                              const int* __restrict__ senders,
                              const int* __restrict__ receivers,
                              int do_relu,
                              float* __restrict__ out) {
    __shared__ float w_lds[64 * 64];      // 16 KB
    __shared__ float e_lds[128 * 66];     // 33.8 KB, pad 66 -> conflict-free te reads
    const int tid = threadIdx.x;
    for (int i = tid; i < 4096; i += 256) w_lds[i] = W[i];
    const int te = tid & 15;        // edge group
    const int tc = tid >> 4;        // channel group 0..15
    const int c0 = tc * 4;
    float4 bv = make_float4(0.f, 0.f, 0.f, 0.f);
    if (bias) bv = *(const float4*)(bias + c0);
    const int srow = tid >> 1, shalf = tid & 1;
    const int ntiles = (M + 127) >> 7;

    for (int t = blockIdx.x; t < ntiles; t += gridDim.x) {
        const int base = t << 7;
        __syncthreads();
        {
            int g = base + srow;
            if (g > M - 1) g = M - 1;
            const float4* src = (const float4*)(A + (size_t)g * 64) + shalf * 8;
            float* dst = &e_lds[srow * 66 + shalf * 32];
            #pragma unroll
            for (int j = 0; j < 8; ++j) {
                float4 v = src[j];
                dst[j * 4 + 0] = v.x; dst[j * 4 + 1] = v.y;
                dst[j * 4 + 2] = v.z; dst[j * 4 + 3] = v.w;
            }
        }
        __syncthreads();

        float4 acc[8];
        #pragma unroll
        for (int i = 0; i < 8; ++i) acc[i] = make_float4(0.f, 0.f, 0.f, 0.f);

        #pragma unroll 4
        for (int k = 0; k < 64; ++k) {
            const float4 wv = *(const float4*)&w_lds[k * 64 + c0];
            #pragma unroll
            for (int i = 0; i < 8; ++i) {
                const float ev = e_lds[(te + 16 * i) * 66 + k];
                acc[i].x = fmaf(ev, wv.x, acc[i].x);
                acc[i].y = fmaf(ev, wv.y, acc[i].y);
                acc[i].z = fmaf(ev, wv.z, acc[i].z);
                acc[i].w = fmaf(ev, wv.w, acc[i].w);
            }
        }

        #pragma unroll
        for (int i = 0; i < 8; ++i) {
            const int e = base + te + 16 * i;
            if (e < M) {
                float4 o = acc[i];
                o.x += bv.x; o.y += bv.y; o.z += bv.z; o.w += bv.w;
                if (P) {
                    const float4 pv = *(const float4*)(P + (size_t)senders[e] * 64 + c0);
                    o.x += pv.x; o.y += pv.y; o.z += pv.z; o.w += pv.w;
                }
                if (Q) {
                    const float4 qv = *(const float4*)(Q + (size_t)receivers[e] * 64 + c0);
                    o.x += qv.x; o.y += qv.y; o.z += qv.z; o.w += qv.w;
                }
                if (do_relu) {
                    o.x = fmaxf(o.x, 0.f); o.y = fmaxf(o.y, 0.f);
                    o.z = fmaxf(o.z, 0.f); o.w = fmaxf(o.w, 0.f);
                }
                *(float4*)(out + (size_t)e * 64 + c0) = o;
            }
        }
    }
}

// ================= segmented mean aggregation (CSR, atomic-free) =================
__launch_bounds__(256, 8)
__global__ void agg_kernel(const float* __restrict__ ebuf, const int* __restrict__ eidx,
                           const int* __restrict__ row_start, const float* __restrict__ inv,
                           float* __restrict__ agg) {
    const int lane = threadIdx.x & 63;
    const int w = (blockIdx.x * 256 + threadIdx.x) >> 6;
    const int nw = (gridDim.x * 256) >> 6;
    for (int v = w; v < NN; v += nw) {
        const int s = row_start[v], e = row_start[v + 1];
        float sum = 0.f;
        #pragma unroll 4
        for (int j = s; j < e; ++j) {
            const int ed = eidx[j];
            sum += ebuf[(size_t)ed * 64 + lane];
        }
        agg[(size_t)v * 64 + lane] = sum * inv[v];
    }
}

// ================= node update: relu([nodes|agg] @ Wn + bn) =================
__launch_bounds__(256, 3)
__global__ void node_kernel(const float* __restrict__ nodes_in,
                            const float* __restrict__ agg,
                            const float* __restrict__ W,     // [128][64]
                            const float* __restrict__ bias,  // [64]
                            float* __restrict__ out) {
    __shared__ float w_lds[128 * 64];   // 32 KB
    __shared__ float e_lds[128 * 33];   // 16.9 KB
    const int tid = threadIdx.x;
    for (int i = tid; i < 8192; i += 256) w_lds[i] = W[i];
    const int te = tid & 15, tc = tid >> 4, c0 = tc * 4;
    const float4 bv = *(const float4*)(bias + c0);
    const int srow = tid >> 1, shalf = tid & 1;
    const int ntiles = (NN + 127) >> 7;

    for (int t = blockIdx.x; t < ntiles; t += gridDim.x) {
        const int base = t << 7;
        float4 acc[8];
        #pragma unroll
        for (int i = 0; i < 8; ++i) acc[i] = make_float4(0.f, 0.f, 0.f, 0.f);

        #pragma unroll
        for (int c = 0; c < 4; ++c) {
            const float* src0 = (c < 2) ? nodes_in : agg;
            const int coff = (c & 1) * 32;
            __syncthreads();
            {
                int g = base + srow;
                if (g > NN - 1) g = NN - 1;
                const float4* src = (const float4*)(src0 + (size_t)g * 64 + coff) + shalf * 4;
                float* dst = &e_lds[srow * 33 + shalf * 16];
                #pragma unroll
                for (int j = 0; j < 4; ++j) {
                    float4 v = src[j];
                    dst[j * 4 + 0] = v.x; dst[j * 4 + 1] = v.y;
                    dst[j * 4 + 2] = v.z; dst[j * 4 + 3] = v.w;
                }
            }
            __syncthreads();
            #pragma unroll 4
            for (int k = 0; k < 32; ++k) {
                const float4 wv = *(const float4*)&w_lds[(c * 32 + k) * 64 + c0];
                #pragma unroll
                for (int i = 0; i < 8; ++i) {
                    const float ev = e_lds[(te + 16 * i) * 33 + k];
                    acc[i].x = fmaf(ev, wv.x, acc[i].x);
                    acc[i].y = fmaf(ev, wv.y, acc[i].y);
                    acc[i].z = fmaf(ev, wv.z, acc[i].z);
                    acc[i].w = fmaf(ev, wv.w, acc[i].w);
                }
            }
        }

        #pragma unroll
        for (int i = 0; i < 8; ++i) {
            const int v = base + te + 16 * i;
            if (v < NN) {
                float4 o = acc[i];
                o.x = fmaxf(o.x + bv.x, 0.f); o.y = fmaxf(o.y + bv.y, 0.f);
                o.z = fmaxf(o.z + bv.z, 0.f); o.w = fmaxf(o.w + bv.w, 0.f);
                *(float4*)(out + (size_t)v * 64 + c0) = o;
            }
        }
    }
}

// ================= final: LN + MLP + projection =================
__launch_bounds__(256, 2)
__global__ void final_kernel(const float* __restrict__ nodes,
                             const float* __restrict__ gamma,
                             const float* __restrict__ beta,
                             const float* __restrict__ W1, const float* __restrict__ b1,
                             const float* __restrict__ W2, const float* __restrict__ b2,
                             const float* __restrict__ Wp, const float* __restrict__ bp,
                             float* __restrict__ out) {
    __shared__ float w1_lds[64 * 128];
    __shared__ float w2_lds[128 * 64];
    const int t = threadIdx.x;
    for (int i = t; i < 64 * 128; i += 256) w1_lds[i] = W1[i];
    for (int i = t; i < 128 * 64; i += 256) w2_lds[i] = W2[i];
    const int lane = t & 63;
    const int wid  = t >> 6;
    const float gm  = gamma[lane], bt = beta[lane];
    const float b1a = b1[lane], b1b = b1[64 + lane];
    const float b2l = b2[lane];
    const float wpl = Wp[lane];
    const float bp0 = bp[0];
    __syncthreads();

    for (int v = blockIdx.x * 4 + wid; v < NN; v += gridDim.x * 4) {
        const float x = nodes[(size_t)v * 64 + lane];
        float s = x;
        #pragma unroll
        for (int off = 32; off; off >>= 1) s += __shfl_xor(s, off, 64);
        const float mu = s * (1.0f / 64.0f);
        const float d  = x - mu;
        float q = d * d;
        #pragma unroll
        for (int off = 32; off; off >>= 1) q += __shfl_xor(q, off, 64);
        const float xn = d * rsqrtf(q * (1.0f / 64.0f) + 1e-5f) * gm + bt;

        float h0 = 0.f, h1 = 0.f;
        #pragma unroll 8
        for (int k = 0; k < 64; ++k) {
            const float xk = __shfl(xn, k, 64);
            h0 += xk * w1_lds[k * 128 + lane];
            h1 += xk * w1_lds[k * 128 + 64 + lane];
        }
        h0 = fmaxf(h0 + b1a, 0.f);
        h1 = fmaxf(h1 + b1b, 0.f);

        float o = 0.f;
        #pragma unroll 8
        for (int k = 0; k < 128; ++k) {
            const float hk = __shfl((k < 64) ? h0 : h1, k & 63, 64);
            o += hk * w2_lds[k * 64 + lane];
        }
        o += b2l;

        float p = o * wpl;
        #pragma unroll
        for (int off = 32; off; off >>= 1) p += __shfl_xor(p, off, 64);
        if (lane == 0) out[v] = p + bp0;
    }
}

extern "C" void kernel_launch(void* const* d_in, const int* in_sizes, int n_in,
                              void* d_out, int out_size, void* d_ws, size_t ws_size,
                              hipStream_t stream) {
    const float* nodes     = (const float*)d_in[0];
    const float* edges     = (const float*)d_in[1];
    const int*   senders   = (const int*)d_in[2];
    const int*   receivers = (const int*)d_in[3];
    const float* We        = (const float*)d_in[4];
    const float* be        = (const float*)d_in[5];
    const float* Wn        = (const float*)d_in[6];
    const float* bn        = (const float*)d_in[7];
    const float* gamma     = (const float*)d_in[8];
    const float* beta      = (const float*)d_in[9];
    const float* W1        = (const float*)d_in[10];
    const float* b1        = (const float*)d_in[11];
    const float* W2        = (const float*)d_in[12];
    const float* b2        = (const float*)d_in[13];
    const float* Wp        = (const float*)d_in[14];
    const float* bp        = (const float*)d_in[15];
    float* out = (float*)d_out;

    float* ws        = (float*)d_ws;
    float* edges_buf = ws;                                  // [NE][64] 204.8 MB
    float* Pbuf      = edges_buf + (size_t)NE * 64;         // [NN][64] 12.8 MB (reused as agg)
    float* Qbuf      = Pbuf + (size_t)NN * 64;              // [NN][64] 12.8 MB
    float* nodes_buf = Qbuf + (size_t)NN * 64;              // [NN][64] 12.8 MB
    int*   cnt_i     = (int*)(nodes_buf + (size_t)NN * 64); // [NN]
    int*   row_start = cnt_i + NN;                          // [NN+1]
    int*   cursor    = row_start + NN + 1;                  // [NN]
    int*   eidx      = cursor + NN;                         // [NE]
    int*   bsum      = eidx + NE;                           // [256]
    float* inv       = (float*)(bsum + 256);                // [NN]
    float* aggbuf    = Pbuf;                                // overlay: P dead when agg written

    hipMemsetAsync(cnt_i, 0, NN * sizeof(int), stream);
    hipMemsetAsync(cursor, 0, NN * sizeof(int), stream);
    hist_kernel<<<(NE + 255) / 256, 256, 0, stream>>>(receivers, cnt_i);
    inv_kernel<<<(NN + 255) / 256, 256, 0, stream>>>(cnt_i, inv);
    scan1_kernel<<<196, 256, 0, stream>>>(cnt_i, row_start, bsum);
    scan2_kernel<<<1, 256, 0, stream>>>(bsum, 196);
    scan3_kernel<<<196, 256, 0, stream>>>(row_start, bsum);
    scatter_kernel<<<(NE + 255) / 256, 256, 0, stream>>>(receivers, row_start, cursor, eidx);

    for (int l = 0; l < 3; ++l) {
        const float* ncur = (l == 0) ? nodes : nodes_buf;
        const float* ecur = (l == 0) ? edges : edges_buf;
        const float* We_l = We + (size_t)l * 192 * 64;
        // P = nodes @ We[64:128], Q = nodes @ We[128:192]
        gemm64_kernel<<<391, 256, 0, stream>>>(ncur, NN, We_l + 64 * 64,
                                               nullptr, nullptr, nullptr, nullptr, nullptr, 0, Pbuf);
        gemm64_kernel<<<391, 256, 0, stream>>>(ncur, NN, We_l + 128 * 64,
                                               nullptr, nullptr, nullptr, nullptr, nullptr, 0, Qbuf);
        // edges = relu(edges @ We[0:64] + P[s] + Q[r] + be)
        gemm64_kernel<<<3125, 256, 0, stream>>>(ecur, NE, We_l,
                                                be + (size_t)l * 64, Pbuf, Qbuf,
                                                senders, receivers, 1, edges_buf);
        // agg = segmented-mean(edges) ; overlays Pbuf (P is dead now)
        agg_kernel<<<2048, 256, 0, stream>>>(edges_buf, eidx, row_start, inv, aggbuf);
        // nodes = relu([nodes|agg] @ Wn + bn)
        node_kernel<<<391, 256, 0, stream>>>(ncur, aggbuf,
                                             Wn + (size_t)l * 128 * 64, bn + (size_t)l * 64,
                                             nodes_buf);
    }
    final_kernel<<<625, 256, 0, stream>>>(nodes_buf, gamma, beta,
                                          W1, b1, W2, b2, Wp, bp, out);
}